// Round 7
// baseline (120.816 us; speedup 1.0000x reference)
//
#include <hip/hip_runtime.h>
#include <math.h>

#define BATCH 8
#define HH 512
#define WW 512
#define IMG (HH * WW)
#define NTOT (BATCH * IMG)
#define TROWS 4
#define TS (TROWS * WW)                      // 2048 px per tile (8 KB LDS)
#define NTILES (NTOT / TS)                   // 1024 tiles per field
#define BPF (BATCH * (HH / TROWS - 1) * WW)  // 520192 border px per field
#define THRESH 0.5f
#define NBLK4 (NTOT / 1024)                  // 2048 blocks for 4-px/thread passes

// ---------- union-find helpers (finds are read-only: safe vs concurrent atomicMin) ----------

__device__ __forceinline__ int findroot_g(const int* p, int x) {
    int px;
    while ((px = p[x]) != x) x = px;
    return x;
}

__device__ __forceinline__ void unite_g(int* p, int a, int b) {
    bool done = false;
    do {
        a = findroot_g(p, a);
        b = findroot_g(p, b);
        if (a > b) {
            int old = atomicMin(&p[a], b);
            done = (old == a);
            a = old;
        } else if (b > a) {
            int old = atomicMin(&p[b], a);
            done = (old == b);
            b = old;
        } else {
            done = true;
        }
    } while (!done);
}

__device__ __forceinline__ int findroot_s(const int* p, int x) {
    int px;
    while ((px = p[x]) != x) x = px;
    return x;
}

__device__ __forceinline__ void unite_s(int* p, int a, int b) {
    bool done = false;
    do {
        a = findroot_s(p, a);
        b = findroot_s(p, b);
        if (a > b) {
            int old = atomicMin(&p[a], b);
            done = (old == a);
            a = old;
        } else if (b > a) {
            int old = atomicMin(&p[b], a);
            done = (old == b);
            b = old;
        } else {
            done = true;
        }
    } while (!done);
}

// ---------- kernel 1: per-tile CCL in LDS (both fields) + zero flag arrays ----------

__global__ void __launch_bounds__(256) k_local(const float* __restrict__ preds,
                                               const float* __restrict__ targets,
                                               int* __restrict__ pP, int* __restrict__ pT,
                                               unsigned long long* __restrict__ flags64) {
    __shared__ int lp[TS];
    int bid = blockIdx.x;
    int field = bid >> 10;                   // 0 = pred, 1 = target (NTILES==1024)
    int tb = bid & (NTILES - 1);
    const float* __restrict__ src = field ? targets : preds;
    int* __restrict__ gp = field ? pT : pP;
    const int base = tb * TS;

    // zero flag bytes: grid is 2048*256 threads, flag region is 4 MB = 524288 u64
    flags64[bid * 256 + threadIdx.x] = 0ull;

    // vectorized init: 2 float4 per thread
    const float4* __restrict__ src4 = (const float4*)(src + base);
    for (int i = threadIdx.x; i < TS / 4; i += 256) {
        float4 v = src4[i];
        int l = 4 * i;
        if (field) {
            lp[l]     = (v.x != 0.0f) ? l     : -1;
            lp[l + 1] = (v.y != 0.0f) ? l + 1 : -1;
            lp[l + 2] = (v.z != 0.0f) ? l + 2 : -1;
            lp[l + 3] = (v.w != 0.0f) ? l + 3 : -1;
        } else {
            lp[l]     = (v.x > THRESH) ? l     : -1;
            lp[l + 1] = (v.y > THRESH) ? l + 1 : -1;
            lp[l + 2] = (v.z > THRESH) ? l + 2 : -1;
            lp[l + 3] = (v.w > THRESH) ? l + 3 : -1;
        }
    }
    __syncthreads();

    // union: right + down, 8 px per thread
    for (int l = threadIdx.x; l < TS; l += 256) {
        if (lp[l] < 0) continue;
        if ((l & (WW - 1)) != WW - 1 && lp[l + 1] >= 0) unite_s(lp, l, l + 1);
        if (l < TS - WW && lp[l + WW] >= 0) unite_s(lp, l, l + WW);
    }
    __syncthreads();

    // flatten to global ids, coalesced write
    for (int l = threadIdx.x; l < TS; l += 256) {
        int out = -1;
        if (lp[l] >= 0) out = base + findroot_s(lp, l);
        gp[base + l] = out;
    }
}

// ---------- kernel 2: unite across tile boundaries (global) ----------

__global__ void k_border(int* __restrict__ pP, int* __restrict__ pT) {
    int id = blockIdx.x * blockDim.x + threadIdx.x;
    if (id >= 2 * BPF) return;
    int field = (id >= BPF) ? 1 : 0;
    int r = id - field * BPF;
    int* p = field ? pT : pP;
    const int perimg = (HH / TROWS - 1) * WW;   // 65024
    int img = r / perimg;
    int rem = r - img * perimg;
    int b = rem >> 9;
    int c = rem & (WW - 1);
    int row = b * TROWS + (TROWS - 1);
    int n = img * IMG + row * WW + c;
    if (p[n] >= 0 && p[n + WW] >= 0) unite_g(p, n, n + WW);
}

// ---------- kernel 3: flatten + mark critical roots, 4 px/thread, vectorized ----------

__global__ void __launch_bounds__(256) k_flatmark(int* __restrict__ pP, int* __restrict__ pT,
                                                  unsigned char* __restrict__ flagP8,
                                                  unsigned char* __restrict__ flagT8,
                                                  int* __restrict__ done_cnt) {
    int n4 = blockIdx.x * blockDim.x + threadIdx.x;
    if (n4 == 0) *done_cnt = 0;      // reset gather completion counter each call
    if (n4 >= NBLK4 * 256) return;

    int4 a4 = ((const int4*)pP)[n4];
    int4 b4 = ((const int4*)pT)[n4];
    int* av = &a4.x;
    int* bv = &b4.x;

    bool achg = false, bchg = false;
#pragma unroll
    for (int k = 0; k < 4; ++k) {
        int a = av[k], b = bv[k];
        if (a >= 0) {
            int r = a, pr;
            while ((pr = pP[r]) != r) r = pr;
            if (a != r) { av[k] = r; achg = true; }
            if (b < 0) flagP8[r] = 1;     // pred fg, target bg -> pred comp critical
        }
        if (b >= 0) {
            int r = b, pr;
            while ((pr = pT[r]) != r) r = pr;
            if (b != r) { bv[k] = r; bchg = true; }
            if (a < 0) flagT8[r] = 1;     // target fg, pred bg -> target comp critical
        }
    }
    if (achg) ((int4*)pP)[n4] = a4;
    if (bchg) ((int4*)pT)[n4] = b4;
}

// ---------- kernel 4: loss + mask blend + partial + fused final reduce ----------

__device__ __forceinline__ float softplusf(float z) {
    return fmaxf(z, 0.0f) + log1pf(expf(-fabsf(z)));
}

__device__ __forceinline__ float block_reduce_sum(float v, float* smem4) {
    for (int off = 32; off > 0; off >>= 1) v += __shfl_down(v, off, 64);
    int lane = threadIdx.x & 63, wid = threadIdx.x >> 6;
    if (lane == 0) smem4[wid] = v;
    __syncthreads();
    return smem4[0] + smem4[1] + smem4[2] + smem4[3];
}

__global__ void __launch_bounds__(256) k_gather(const float* __restrict__ preds,
                                                const float* __restrict__ targets,
                                                const int* __restrict__ pP,
                                                const int* __restrict__ pT,
                                                const unsigned char* __restrict__ flagP8,
                                                const unsigned char* __restrict__ flagT8,
                                                float* __restrict__ partial,
                                                int* __restrict__ done_cnt,
                                                float* __restrict__ out) {
    int n4 = blockIdx.x * blockDim.x + threadIdx.x;
    float4 x4 = ((const float4*)preds)[n4];
    float4 t4 = ((const float4*)targets)[n4];
    int4 a4 = ((const int4*)pP)[n4];
    int4 b4 = ((const int4*)pT)[n4];
    const float* xv = &x4.x;
    const float* tv = &t4.x;
    const int* av = &a4.x;
    const int* bv = &b4.x;

    float contrib = 0.0f;
#pragma unroll
    for (int k = 0; k < 4; ++k) {
        float x = xv[k], t = tv[k];
        float loss = t * softplusf(-x) + (1.0f - t) * softplusf(x);
        float m = 0.0f;
        int b = bv[k];
        if (b >= 0 && flagT8[b]) m += 0.5f;   // BETA * neg
        int a = av[k];
        if (a >= 0 && flagP8[a]) m += 0.5f;   // (1-BETA) * pos
        contrib += (0.5f + 0.5f * m) * loss;  // (1-a)L + a*m*L, a=0.5
    }

    __shared__ float smem4[4];
    float s = block_reduce_sum(contrib, smem4);
    __shared__ bool amLast;
    if (threadIdx.x == 0) {
        partial[blockIdx.x] = s;
        __threadfence();
        int ticket = atomicAdd(done_cnt, 1);
        amLast = (ticket == NBLK4 - 1);
    }
    __syncthreads();
    if (amLast) {
        float acc = 0.0f;
        for (int i = threadIdx.x; i < NBLK4; i += 256) acc += partial[i];
        __syncthreads();  // reuse smem4 safely
        float tot = block_reduce_sum(acc, smem4);
        if (threadIdx.x == 0) out[0] = tot / (float)NTOT;
    }
}

// ---------- launch ----------

extern "C" void kernel_launch(void* const* d_in, const int* in_sizes, int n_in,
                              void* d_out, int out_size, void* d_ws, size_t ws_size,
                              hipStream_t stream) {
    const float* preds = (const float*)d_in[0];
    const float* targets = (const float*)d_in[1];

    int* pP = (int*)d_ws;                                 // 8 MB
    int* pT = pP + NTOT;                                  // 8 MB
    unsigned char* flagP8 = (unsigned char*)(pT + NTOT);  // 2 MB
    unsigned char* flagT8 = flagP8 + NTOT;                // 2 MB (contiguous with flagP8)
    float* partial = (float*)(flagT8 + NTOT);             // 8 KB (2048 floats)
    int* done_cnt = (int*)(partial + NBLK4);              // 4 B
    float* out = (float*)d_out;

    const int block = 256;

    k_local<<<2 * NTILES, block, 0, stream>>>(preds, targets, pP, pT,
                                              (unsigned long long*)flagP8);
    k_border<<<(2 * BPF + block - 1) / block, block, 0, stream>>>(pP, pT);
    k_flatmark<<<NBLK4, block, 0, stream>>>(pP, pT, flagP8, flagT8, done_cnt);
    k_gather<<<NBLK4, block, 0, stream>>>(preds, targets, pP, pT, flagP8, flagT8,
                                          partial, done_cnt, out);
}

// Round 8
// 89.679 us; speedup vs baseline: 1.3472x; 1.3472x over previous
//
#include <hip/hip_runtime.h>
#include <math.h>

#define BATCH 8
#define HH 512
#define WW 512
#define IMG (HH * WW)
#define NTOT (BATCH * IMG)
#define TROWS 4
#define TS (TROWS * WW)                      // 2048 px per tile (8 KB LDS)
#define NTILES (NTOT / TS)                   // 1024 tiles per field
#define BPF (BATCH * (HH / TROWS - 1) * WW)  // 520192 border px per field
#define THRESH 0.5f
#define NBLK4 (NTOT / 1024)                  // 2048 blocks for 4-px/thread passes

// ---------- union-find helpers (finds are read-only: safe vs concurrent atomicMin) ----------

__device__ __forceinline__ int findroot_g(const int* p, int x) {
    int px;
    while ((px = p[x]) != x) x = px;
    return x;
}

__device__ __forceinline__ void unite_g(int* p, int a, int b) {
    bool done = false;
    do {
        a = findroot_g(p, a);
        b = findroot_g(p, b);
        if (a > b) {
            int old = atomicMin(&p[a], b);
            done = (old == a);
            a = old;
        } else if (b > a) {
            int old = atomicMin(&p[b], a);
            done = (old == b);
            b = old;
        } else {
            done = true;
        }
    } while (!done);
}

__device__ __forceinline__ int findroot_s(const int* p, int x) {
    int px;
    while ((px = p[x]) != x) x = px;
    return x;
}

__device__ __forceinline__ void unite_s(int* p, int a, int b) {
    bool done = false;
    do {
        a = findroot_s(p, a);
        b = findroot_s(p, b);
        if (a > b) {
            int old = atomicMin(&p[a], b);
            done = (old == a);
            a = old;
        } else if (b > a) {
            int old = atomicMin(&p[b], a);
            done = (old == b);
            b = old;
        } else {
            done = true;
        }
    } while (!done);
}

// ---------- kernel 1: per-tile CCL in LDS (both fields) + zero flag arrays ----------

__global__ void __launch_bounds__(256) k_local(const float* __restrict__ preds,
                                               const float* __restrict__ targets,
                                               int* __restrict__ pP, int* __restrict__ pT,
                                               unsigned long long* __restrict__ flags64) {
    __shared__ int lp[TS];
    int bid = blockIdx.x;
    int field = bid >> 10;                   // 0 = pred, 1 = target (NTILES==1024)
    int tb = bid & (NTILES - 1);
    const float* __restrict__ src = field ? targets : preds;
    int* __restrict__ gp = field ? pT : pP;
    const int base = tb * TS;

    // zero flag bytes: grid is 2048*256 threads, flag region is 4 MB = 524288 u64
    flags64[bid * 256 + threadIdx.x] = 0ull;

    // vectorized init: 2 float4 per thread
    const float4* __restrict__ src4 = (const float4*)(src + base);
    for (int i = threadIdx.x; i < TS / 4; i += 256) {
        float4 v = src4[i];
        int l = 4 * i;
        if (field) {
            lp[l]     = (v.x != 0.0f) ? l     : -1;
            lp[l + 1] = (v.y != 0.0f) ? l + 1 : -1;
            lp[l + 2] = (v.z != 0.0f) ? l + 2 : -1;
            lp[l + 3] = (v.w != 0.0f) ? l + 3 : -1;
        } else {
            lp[l]     = (v.x > THRESH) ? l     : -1;
            lp[l + 1] = (v.y > THRESH) ? l + 1 : -1;
            lp[l + 2] = (v.z > THRESH) ? l + 2 : -1;
            lp[l + 3] = (v.w > THRESH) ? l + 3 : -1;
        }
    }
    __syncthreads();

    // union: right + down, 8 px per thread
    for (int l = threadIdx.x; l < TS; l += 256) {
        if (lp[l] < 0) continue;
        if ((l & (WW - 1)) != WW - 1 && lp[l + 1] >= 0) unite_s(lp, l, l + 1);
        if (l < TS - WW && lp[l + WW] >= 0) unite_s(lp, l, l + WW);
    }
    __syncthreads();

    // flatten to global ids, coalesced write
    for (int l = threadIdx.x; l < TS; l += 256) {
        int out = -1;
        if (lp[l] >= 0) out = base + findroot_s(lp, l);
        gp[base + l] = out;
    }
}

// ---------- kernel 2: unite across tile boundaries (global) ----------

__global__ void k_border(int* __restrict__ pP, int* __restrict__ pT) {
    int id = blockIdx.x * blockDim.x + threadIdx.x;
    if (id >= 2 * BPF) return;
    int field = (id >= BPF) ? 1 : 0;
    int r = id - field * BPF;
    int* p = field ? pT : pP;
    const int perimg = (HH / TROWS - 1) * WW;   // 65024
    int img = r / perimg;
    int rem = r - img * perimg;
    int b = rem >> 9;
    int c = rem & (WW - 1);
    int row = b * TROWS + (TROWS - 1);
    int n = img * IMG + row * WW + c;
    if (p[n] >= 0 && p[n + WW] >= 0) unite_g(p, n, n + WW);
}

// ---------- kernel 3: flatten + mark critical roots, 4 px/thread, vectorized ----------

__global__ void __launch_bounds__(256) k_flatmark(int* __restrict__ pP, int* __restrict__ pT,
                                                  unsigned char* __restrict__ flagP8,
                                                  unsigned char* __restrict__ flagT8) {
    int n4 = blockIdx.x * blockDim.x + threadIdx.x;

    int4 a4 = ((const int4*)pP)[n4];
    int4 b4 = ((const int4*)pT)[n4];
    int* av = &a4.x;
    int* bv = &b4.x;

    bool achg = false, bchg = false;
#pragma unroll
    for (int k = 0; k < 4; ++k) {
        int a = av[k], b = bv[k];
        if (a >= 0) {
            int r = a, pr;
            while ((pr = pP[r]) != r) r = pr;
            if (a != r) { av[k] = r; achg = true; }
            if (b < 0) flagP8[r] = 1;     // pred fg, target bg -> pred comp critical
        }
        if (b >= 0) {
            int r = b, pr;
            while ((pr = pT[r]) != r) r = pr;
            if (b != r) { bv[k] = r; bchg = true; }
            if (a < 0) flagT8[r] = 1;     // target fg, pred bg -> target comp critical
        }
    }
    if (achg) ((int4*)pP)[n4] = a4;
    if (bchg) ((int4*)pT)[n4] = b4;
}

// ---------- kernel 4: loss + mask blend + per-block partial (deterministic) ----------

__device__ __forceinline__ float softplusf(float z) {
    return fmaxf(z, 0.0f) + log1pf(expf(-fabsf(z)));
}

__device__ __forceinline__ float block_reduce_sum(float v, float* smem4) {
    for (int off = 32; off > 0; off >>= 1) v += __shfl_down(v, off, 64);
    int lane = threadIdx.x & 63, wid = threadIdx.x >> 6;
    if (lane == 0) smem4[wid] = v;
    __syncthreads();
    return smem4[0] + smem4[1] + smem4[2] + smem4[3];
}

__global__ void __launch_bounds__(256) k_gather(const float* __restrict__ preds,
                                                const float* __restrict__ targets,
                                                const int* __restrict__ pP,
                                                const int* __restrict__ pT,
                                                const unsigned char* __restrict__ flagP8,
                                                const unsigned char* __restrict__ flagT8,
                                                float* __restrict__ partial) {
    int n4 = blockIdx.x * blockDim.x + threadIdx.x;
    float4 x4 = ((const float4*)preds)[n4];
    float4 t4 = ((const float4*)targets)[n4];
    int4 a4 = ((const int4*)pP)[n4];
    int4 b4 = ((const int4*)pT)[n4];
    const float* xv = &x4.x;
    const float* tv = &t4.x;
    const int* av = &a4.x;
    const int* bv = &b4.x;

    float contrib = 0.0f;
#pragma unroll
    for (int k = 0; k < 4; ++k) {
        float x = xv[k], t = tv[k];
        float loss = t * softplusf(-x) + (1.0f - t) * softplusf(x);
        float m = 0.0f;
        int b = bv[k];
        if (b >= 0 && flagT8[b]) m += 0.5f;   // BETA * neg
        int a = av[k];
        if (a >= 0 && flagP8[a]) m += 0.5f;   // (1-BETA) * pos
        contrib += (0.5f + 0.5f * m) * loss;  // (1-a)L + a*m*L, a=0.5
    }

    __shared__ float smem4[4];
    float s = block_reduce_sum(contrib, smem4);
    if (threadIdx.x == 0) partial[blockIdx.x] = s;
}

__global__ void k_final(const float* __restrict__ partial, float* __restrict__ out) {
    float s = 0.0f;
    for (int i = threadIdx.x; i < NBLK4; i += 256) s += partial[i];
    __shared__ float smem4[4];
    float tot = block_reduce_sum(s, smem4);
    if (threadIdx.x == 0) out[0] = tot / (float)NTOT;
}

// ---------- launch ----------

extern "C" void kernel_launch(void* const* d_in, const int* in_sizes, int n_in,
                              void* d_out, int out_size, void* d_ws, size_t ws_size,
                              hipStream_t stream) {
    const float* preds = (const float*)d_in[0];
    const float* targets = (const float*)d_in[1];

    int* pP = (int*)d_ws;                                 // 8 MB
    int* pT = pP + NTOT;                                  // 8 MB
    unsigned char* flagP8 = (unsigned char*)(pT + NTOT);  // 2 MB
    unsigned char* flagT8 = flagP8 + NTOT;                // 2 MB (contiguous with flagP8)
    float* partial = (float*)(flagT8 + NTOT);             // 8 KB (2048 floats)
    float* out = (float*)d_out;

    const int block = 256;

    k_local<<<2 * NTILES, block, 0, stream>>>(preds, targets, pP, pT,
                                              (unsigned long long*)flagP8);
    k_border<<<(2 * BPF + block - 1) / block, block, 0, stream>>>(pP, pT);
    k_flatmark<<<NBLK4, block, 0, stream>>>(pP, pT, flagP8, flagT8);
    k_gather<<<NBLK4, block, 0, stream>>>(preds, targets, pP, pT, flagP8, flagT8, partial);
    k_final<<<1, 256, 0, stream>>>(partial, out);
}

// Round 9
// 76.293 us; speedup vs baseline: 1.5836x; 1.1755x over previous
//
#include <hip/hip_runtime.h>
#include <math.h>

#define BATCH 8
#define HH 512
#define WW 512
#define IMG (HH * WW)
#define NTOT (BATCH * IMG)
#define TROWS 4
#define TS (TROWS * WW)                      // 2048 px per tile (8 KB LDS)
#define NTILES (NTOT / TS)                   // 1024 tiles per field
#define BPF (BATCH * (HH / TROWS - 1) * WW)  // 520192 border px per field
#define THRESH 0.5f
#define NBLK (NTOT / 256)                    // 8192 blocks for scalar passes

// ---------- union-find helpers (finds are read-only: safe vs concurrent atomicMin) ----------

__device__ __forceinline__ int findroot_g(const int* p, int x) {
    int px;
    while ((px = p[x]) != x) x = px;
    return x;
}

__device__ __forceinline__ void unite_g(int* p, int a, int b) {
    bool done = false;
    do {
        a = findroot_g(p, a);
        b = findroot_g(p, b);
        if (a > b) {
            int old = atomicMin(&p[a], b);
            done = (old == a);
            a = old;
        } else if (b > a) {
            int old = atomicMin(&p[b], a);
            done = (old == b);
            b = old;
        } else {
            done = true;
        }
    } while (!done);
}

__device__ __forceinline__ int findroot_s(const int* p, int x) {
    int px;
    while ((px = p[x]) != x) x = px;
    return x;
}

__device__ __forceinline__ void unite_s(int* p, int a, int b) {
    bool done = false;
    do {
        a = findroot_s(p, a);
        b = findroot_s(p, b);
        if (a > b) {
            int old = atomicMin(&p[a], b);
            done = (old == a);
            a = old;
        } else if (b > a) {
            int old = atomicMin(&p[b], a);
            done = (old == b);
            b = old;
        } else {
            done = true;
        }
    } while (!done);
}

// ---------- kernel 1: per-tile CCL in LDS via ballot runs + zero flag arrays ----------

__global__ void __launch_bounds__(256) k_local(const float* __restrict__ preds,
                                               const float* __restrict__ targets,
                                               int* __restrict__ pP, int* __restrict__ pT,
                                               unsigned long long* __restrict__ flags64) {
    __shared__ int lp[TS];
    int bid = blockIdx.x;
    int field = bid >> 10;                   // 0 = pred, 1 = target (NTILES==1024)
    int tb = bid & (NTILES - 1);
    const float* __restrict__ src = field ? targets : preds;
    int* __restrict__ gp = field ? pT : pP;
    const int base = tb * TS;

    // zero flag bytes: grid is 2048*256 threads, flag region is 4 MB = 524288 u64
    flags64[bid * 256 + threadIdx.x] = 0ull;

    // init: fg -> self, bg -> -1 (vectorized loads)
    const float4* __restrict__ src4 = (const float4*)(src + base);
    for (int i = threadIdx.x; i < TS / 4; i += 256) {
        float4 v = src4[i];
        int l = 4 * i;
        if (field) {
            lp[l]     = (v.x != 0.0f) ? l     : -1;
            lp[l + 1] = (v.y != 0.0f) ? l + 1 : -1;
            lp[l + 2] = (v.z != 0.0f) ? l + 2 : -1;
            lp[l + 3] = (v.w != 0.0f) ? l + 3 : -1;
        } else {
            lp[l]     = (v.x > THRESH) ? l     : -1;
            lp[l + 1] = (v.y > THRESH) ? l + 1 : -1;
            lp[l + 2] = (v.z > THRESH) ? l + 2 : -1;
            lp[l + 3] = (v.w > THRESH) ? l + 3 : -1;
        }
    }
    __syncthreads();

    const int lane = threadIdx.x & 63;

    // U1: horizontal run leaders via wave ballot; plain stores, sign-stable races only.
    // Each wave chunk covers 64 consecutive pixels of one row (WW=512 is a multiple of 64).
    for (int l = threadIdx.x; l < TS; l += 256) {
        int wbase = l & ~63;
        bool fg = lp[l] >= 0;
        unsigned long long m = __ballot(fg);
        int col0 = wbase & (WW - 1);                         // col of lane 0
        bool left0 = (col0 != 0) && (lp[wbase - 1] >= 0);    // broadcast LDS read
        unsigned long long starts = m & ~(m << 1);
        if (left0) starts &= ~1ull;                          // run continues from prev chunk
        unsigned long long below = starts & (~0ull >> (63 - lane));
        if (fg) {
            int dst = below ? (wbase + (63 - __clzll(below)))  // in-chunk leader
                            : (wbase - 1);                     // chain into previous chunk
            lp[l] = dst;
        }
    }
    __syncthreads();

    // U2: vertical unions, one per run-adjacency (dedup: skip if left pair also fg-fg)
    for (int l = threadIdx.x; l < TS - WW; l += 256) {
        if (lp[l] < 0 || lp[l + WW] < 0) continue;
        int col = l & (WW - 1);
        if (col != 0 && lp[l - 1] >= 0 && lp[l + WW - 1] >= 0) continue;  // covered by left
        unite_s(lp, l, l + WW);
    }
    __syncthreads();

    // flatten to global ids, coalesced write
    for (int l = threadIdx.x; l < TS; l += 256) {
        int out = -1;
        if (lp[l] >= 0) out = base + findroot_s(lp, l);
        gp[base + l] = out;
    }
}

// ---------- kernel 2: unite across tile boundaries (on stored tile-roots) ----------

__global__ void k_border(int* __restrict__ pP, int* __restrict__ pT) {
    int id = blockIdx.x * blockDim.x + threadIdx.x;
    if (id >= 2 * BPF) return;
    int field = (id >= BPF) ? 1 : 0;
    int r = id - field * BPF;
    int* p = field ? pT : pP;
    const int perimg = (HH / TROWS - 1) * WW;   // 65024
    int img = r / perimg;
    int rem = r - img * perimg;
    int b = rem >> 9;
    int c = rem & (WW - 1);
    int row = b * TROWS + (TROWS - 1);
    int n = img * IMG + row * WW + c;
    int ra = p[n];
    int rb = p[n + WW];
    if (ra >= 0 && rb >= 0) unite_g(p, ra, rb);   // skip the pixel->tileroot hop
}

// ---------- kernel 3: flatten parents + mark critical roots (plain byte stores, no RMW) ----------

__global__ void k_flatmark(int* __restrict__ pP, int* __restrict__ pT,
                           unsigned char* __restrict__ flagP8,
                           unsigned char* __restrict__ flagT8) {
    int n = blockIdx.x * blockDim.x + threadIdx.x;
    if (n >= NTOT) return;
    int a = pP[n];
    int b = pT[n];
    bool fp = a >= 0;
    bool ft = b >= 0;
    if (fp) {
        int r = a, pr;
        while ((pr = pP[r]) != r) r = pr;
        if (a != r) pP[n] = r;
        if (!ft) flagP8[r] = 1;   // same-value races benign, no RMW
    }
    if (ft) {
        int r = b, pr;
        while ((pr = pT[r]) != r) r = pr;
        if (b != r) pT[n] = r;
        if (!fp) flagT8[r] = 1;
    }
}

// ---------- kernel 4: loss + mask blend + per-block partial (deterministic) ----------

__device__ __forceinline__ float softplusf(float z) {
    return fmaxf(z, 0.0f) + log1pf(expf(-fabsf(z)));
}

__device__ __forceinline__ float block_reduce_sum(float v, float* smem4) {
    for (int off = 32; off > 0; off >>= 1) v += __shfl_down(v, off, 64);
    int lane = threadIdx.x & 63, wid = threadIdx.x >> 6;
    if (lane == 0) smem4[wid] = v;
    __syncthreads();
    return smem4[0] + smem4[1] + smem4[2] + smem4[3];
}

__global__ void k_gather(const float* __restrict__ preds, const float* __restrict__ targets,
                         const int* __restrict__ pP, const int* __restrict__ pT,
                         const unsigned char* __restrict__ flagP8,
                         const unsigned char* __restrict__ flagT8,
                         float* __restrict__ partial) {
    int n = blockIdx.x * blockDim.x + threadIdx.x;
    float contrib = 0.0f;
    if (n < NTOT) {
        float x = preds[n];
        float t = targets[n];
        float loss = t * softplusf(-x) + (1.0f - t) * softplusf(x);
        int a = pP[n];   // final root after k_flatmark compression
        int b = pT[n];
        float m = 0.0f;
        if (b >= 0 && flagT8[b]) m += 0.5f;   // BETA * neg
        if (a >= 0 && flagP8[a]) m += 0.5f;   // (1-BETA) * pos
        contrib = (0.5f + 0.5f * m) * loss;   // (1-a)L + a*m*L, a=0.5
    }
    __shared__ float smem4[4];
    float s = block_reduce_sum(contrib, smem4);
    if (threadIdx.x == 0) partial[blockIdx.x] = s;
}

__global__ void k_final(const float* __restrict__ partial, float* __restrict__ out) {
    float s = 0.0f;
    for (int i = threadIdx.x; i < NBLK; i += 256) s += partial[i];
    __shared__ float smem4[4];
    float tot = block_reduce_sum(s, smem4);
    if (threadIdx.x == 0) out[0] = tot / (float)NTOT;
}

// ---------- launch ----------

extern "C" void kernel_launch(void* const* d_in, const int* in_sizes, int n_in,
                              void* d_out, int out_size, void* d_ws, size_t ws_size,
                              hipStream_t stream) {
    const float* preds = (const float*)d_in[0];
    const float* targets = (const float*)d_in[1];

    int* pP = (int*)d_ws;                                 // 8 MB
    int* pT = pP + NTOT;                                  // 8 MB
    unsigned char* flagP8 = (unsigned char*)(pT + NTOT);  // 2 MB
    unsigned char* flagT8 = flagP8 + NTOT;                // 2 MB (contiguous with flagP8)
    float* partial = (float*)(flagT8 + NTOT);             // 32 KB
    float* out = (float*)d_out;

    const int block = 256;

    k_local<<<2 * NTILES, block, 0, stream>>>(preds, targets, pP, pT,
                                              (unsigned long long*)flagP8);
    k_border<<<(2 * BPF + block - 1) / block, block, 0, stream>>>(pP, pT);
    k_flatmark<<<NBLK, block, 0, stream>>>(pP, pT, flagP8, flagT8);
    k_gather<<<NBLK, block, 0, stream>>>(preds, targets, pP, pT, flagP8, flagT8, partial);
    k_final<<<1, 256, 0, stream>>>(partial, out);
}